// Round 4
// baseline (738.976 us; speedup 1.0000x reference)
//
#include <hip/hip_runtime.h>
#include <cstdint>
#include <cstddef>

#define RN 200000   // nodes per side (NU == NI)
#define NR2 400000  // both sides
#define DIM 64
#define NE 1000000  // edges per relation
#define NB_PR 391   // buckets per relation (512 rows each; 391*512 >= 200000)
#define NB 782      // total buckets (go: 0..390, back: 391..781)
#define NSEG (NB*8) // per-(bucket, virtual-XCD) segments = 6256

typedef __attribute__((ext_vector_type(8))) short short8v;   // 8 x bf16 fragment (4 VGPR)
typedef __attribute__((ext_vector_type(4))) float f32x4;
typedef __attribute__((ext_vector_type(8))) unsigned short us8;

struct Ptrs16 { const void* p[16]; };

__device__ __forceinline__ float bf2f(unsigned short u){
  unsigned int x = ((unsigned int)u) << 16;
  return __builtin_bit_cast(float, x);
}
__device__ __forceinline__ unsigned short f2bf(float f){
  unsigned int x = __builtin_bit_cast(unsigned int, f);
  unsigned int r = x + 0x7fffu + ((x >> 16) & 1u);   // RNE (values are finite/sane here)
  return (unsigned short)(r >> 16);
}

// ---- dtype sniffing: flags[0]=1 if floats are bf16, flags[1]=1 if indices are int64 ----
__global__ __launch_bounds__(256) void detect_k(const unsigned short* emb,
                                                const unsigned int* esrc,
                                                int* flags){
  __shared__ int cnt0, cnt1;
  int t = threadIdx.x;
  if (t == 0){ cnt0 = 0; cnt1 = 0; }
  __syncthreads();
  int c0 = 0, c1 = 0;
  #pragma unroll
  for (int s = 0; s < 4; ++s){
    int i = (t*4 + s) * 14;                 // even uint16 index
    float af = fabsf(bf2f(emb[i]));
    if (af > 0.0009765625f && af < 32.0f) c0++;
    int e = t*4 + s;
    if (esrc[2*e + 1] != 0u) c1++;          // int64 high words are 0
  }
  atomicAdd(&cnt0, c0); atomicAdd(&cnt1, c1);
  __syncthreads();
  if (t == 0){
    flags[0] = (cnt0 > 512) ? 1 : 0;
    flags[1] = (cnt1 < 512) ? 1 : 0;
  }
}

__global__ __launch_bounds__(256) void zero_k(int* p, int n){
  int i = blockIdx.x*256 + threadIdx.x;
  if (i < n) p[i] = 0;
}

// ---- canonicalize the 16 small param arrays (inputs 2..17) to fp32 ----
__global__ __launch_bounds__(256) void conv_params_k(Ptrs16 ps, const int* flags, float* out){
  const int offs[17] = {0,12288,12352,24640,24704,36992,37056,49344,49408,49472,
                        49536,49600,49664,49728,49792,49856,49920};
  int i = blockIdx.x*256 + threadIdx.x;
  if (i >= 49920) return;
  int a = 0;
  while (i >= offs[a+1]) ++a;
  int j = i - offs[a];
  float v = flags[0] ? bf2f(((const unsigned short*)ps.p[a])[j])
                     : ((const float*)ps.p[a])[j];
  out[i] = v;
}

// ---- canonicalize embeddings to internal bf16 ----
__global__ __launch_bounds__(256) void conv_emb_k(const void* in, unsigned short* out,
                                                  const int* flags, int n8){
  int i = blockIdx.x*256 + threadIdx.x;
  if (i >= n8) return;
  us8 o;
  if (flags[0]){
    o = ((const us8*)in)[i];
  } else {
    const float* f = (const float*)in + (size_t)i*8;
    #pragma unroll
    for (int r = 0; r < 8; ++r) o[r] = f2bf(f[r]);
  }
  ((us8*)out)[i] = o;
}

// ==== CSR build, XCD-local two-phase (R4) ====
// Phase A1: histogram edges into (virtual-XCD v = bid&7, bucket) segments.
// Counters bcnt[v*NB+b]: each v's 3KB block is only touched by blocks on one XCD.
__global__ __launch_bounds__(256) void countA_k(const unsigned int* go_dst,
                                                const unsigned int* back_dst,
                                                int* bcnt, const int* flags){
  int e = blockIdx.x*256 + threadIdx.x;
  if (e >= 2*NE) return;
  int i64 = flags[1];
  int rel = (e >= NE);
  int ei  = rel ? e - NE : e;
  const unsigned int* pd = rel ? back_dst : go_dst;
  int d = i64 ? (int)__builtin_nontemporal_load(&pd[2*ei]) : (int)__builtin_nontemporal_load(&pd[ei]);
  int b = (rel ? NB_PR : 0) + (d >> 9);
  int v = blockIdx.x & 7;
  atomicAdd(&bcnt[v*NB + b], 1);
}

// Phase A2: exclusive scan of the 6256 segment counts in (bucket,major; v,minor)
// order -> pairs array is grouped by bucket (contiguous), sub-grouped by v.
// Also: bucket b's col base == pseg[b*8] (edges before bucket b).
__global__ __launch_bounds__(1024) void scanTiny_k(const int* bcnt, int* pseg, int* pcur, int* rs){
  __shared__ int sh[1024];
  int t = threadIdx.x;
  int loc[7]; int sum = 0;
  #pragma unroll
  for (int j = 0; j < 7; ++j){
    int s = t*7 + j;
    int val = 0;
    if (s < NSEG){ int b = s >> 3, v = s & 7; val = bcnt[v*NB + b]; }
    loc[j] = sum; sum += val;
  }
  sh[t] = sum;
  __syncthreads();
  for (int o = 1; o < 1024; o <<= 1){
    int x = (t >= o) ? sh[t-o] : 0;
    __syncthreads();
    sh[t] += x;
    __syncthreads();
  }
  int base = (t > 0) ? sh[t-1] : 0;
  #pragma unroll
  for (int j = 0; j < 7; ++j){
    int s = t*7 + j;
    if (s < NSEG){
      int p = base + loc[j];
      pseg[s] = p;
      int b = s >> 3, v = s & 7;
      pcur[v*NB + b] = p;
    }
  }
  if (t == 0){ pseg[NSEG] = 2*NE; rs[NR2] = 2*NE; }
}

// Phase A3: scatter (src, concat-row) pairs into XCD-local bucket segments.
// Normal (cached) stores: each (v,b) stream is written by one XCD -> lines
// fill in that XCD's L2 -> full-line writebacks (kills the 16x amplification).
__global__ __launch_bounds__(256) void scatterA_k(const unsigned int* go_src, const unsigned int* go_dst,
                                                  const unsigned int* back_src, const unsigned int* back_dst,
                                                  int* pcur, uint2* pairs, const int* flags){
  int e = blockIdx.x*256 + threadIdx.x;
  if (e >= 2*NE) return;
  int i64 = flags[1];
  int rel = (e >= NE);
  int ei  = rel ? e - NE : e;
  const unsigned int* pd = rel ? back_dst : go_dst;
  const unsigned int* ps = rel ? back_src : go_src;
  int d = i64 ? (int)__builtin_nontemporal_load(&pd[2*ei]) : (int)__builtin_nontemporal_load(&pd[ei]);
  int s = i64 ? (int)__builtin_nontemporal_load(&ps[2*ei]) : (int)__builtin_nontemporal_load(&ps[ei]);
  int row = (rel ? RN : 0) + d;
  int b = (rel ? NB_PR : 0) + (d >> 9);
  int v = blockIdx.x & 7;
  int p = atomicAdd(&pcur[v*NB + b], 1);
  pairs[p] = make_uint2((unsigned int)s, (unsigned int)row);
}

// Phase B: one workgroup per bucket builds that bucket's CSR slice entirely
// from L2-resident data: LDS row-histogram + LDS scan + LDS-cursor scatter
// into the bucket's ~10KB contiguous col range.
__global__ __launch_bounds__(512) void buildCSR_k(const int* __restrict__ pseg,
                                                  const uint2* __restrict__ pairs,
                                                  int* __restrict__ rs, int* __restrict__ col){
  __shared__ int lcnt[512];
  __shared__ int lsc[512];
  __shared__ int lcur[512];
  int b = blockIdx.x, t = threadIdx.x;
  int relEnd = (b < NB_PR) ? RN : NR2;
  int d0 = (b < NB_PR) ? b*512 : RN + (b - NB_PR)*512;
  int rows = relEnd - d0; if (rows > 512) rows = 512;
  int s0   = pseg[b*8];        // bucket edges are contiguous: [s0, sEnd)
  int sEnd = pseg[b*8 + 8];
  lcnt[t] = 0;
  __syncthreads();
  for (int i = s0 + t; i < sEnd; i += 512){
    uint2 q = pairs[i];
    atomicAdd(&lcnt[(int)q.y - d0], 1);
  }
  __syncthreads();
  int v = lcnt[t];
  lsc[t] = v;
  __syncthreads();
  for (int o = 1; o < 512; o <<= 1){
    int x = (t >= o) ? lsc[t-o] : 0;
    __syncthreads();
    lsc[t] += x;
    __syncthreads();
  }
  int start = lsc[t] - v;          // exclusive prefix within bucket
  lcur[t] = start;
  if (t < rows) rs[d0 + t] = s0 + start;
  __syncthreads();
  for (int i = s0 + t; i < sEnd; i += 512){
    uint2 q = pairs[i];
    int r = (int)q.y - d0;
    int p = atomicAdd(&lcur[r], 1);
    col[s0 + p] = (int)q.x;
  }
}

// ---- SpMM: one wave per dst row; agg = deg^-1/2 * sum_src X[src] (bf16 out) ----
__global__ __launch_bounds__(256) void spmm_k(const int* __restrict__ rs, const int* __restrict__ col,
                                              const unsigned short* __restrict__ X,
                                              unsigned short* __restrict__ agg){
  int w = (int)((blockIdx.x*256 + threadIdx.x) >> 6);
  int lane = threadIdx.x & 63;
  if (w >= RN) return;
  int b = __builtin_amdgcn_readfirstlane(rs[w]);
  int e = __builtin_amdgcn_readfirstlane(rs[w+1]);
  float acc = 0.0f;
  for (int i = b; i < e; i += 8){
    int rem = e - i;                       // wave-uniform
    int idx0 = __builtin_nontemporal_load(&col[i]);
    int idx[8];
    idx[0] = idx0;
    #pragma unroll
    for (int j = 1; j < 8; ++j)
      idx[j] = (j < rem) ? __builtin_nontemporal_load(&col[i + j]) : idx0;  // clamp tail
    float v[8];
    #pragma unroll
    for (int j = 0; j < 8; ++j)
      v[j] = bf2f(X[((size_t)(unsigned)idx[j] << 6) + lane]);
    #pragma unroll
    for (int j = 0; j < 8; ++j)
      acc += (j < rem) ? v[j] : 0.0f;
  }
  int dg = e - b;
  float nrm = dg > 0 ? rsqrtf((float)dg) : 1.0f;
  __builtin_nontemporal_store(f2bf(acc * nrm), &agg[((size_t)w << 6) + lane]);
}

// ---- GEMM: H = Xd@W[0:64] + Ag@W[64:128] + b, bf16 out (maybe in-place into Ag),
//      fused BN sum/sumsq stats. Wave tile = 16 rows x 64 cols, mfma 16x16x32 bf16. ----
__global__ __launch_bounds__(256) void gemm_k(const unsigned short* __restrict__ Xd,
                                              const unsigned short* Ag,           // may alias Hout
                                              const float* __restrict__ W,
                                              const float* __restrict__ bias,
                                              unsigned short* Hout,
                                              float* __restrict__ stats){
  __shared__ float ls[128];
  for (int t0 = threadIdx.x; t0 < 128; t0 += 256) ls[t0] = 0.0f;
  __syncthreads();
  int lane = threadIdx.x & 63;
  int gw = (int)((blockIdx.x*256 + threadIdx.x) >> 6);
  int nw = (int)(gridDim.x * 4);
  int c16 = lane & 15, kg = lane >> 4;

  // B fragments for all 4 col-tiles x K=128 (built once per wave; W is tiny & cached)
  short8v Bf[2][2][4];
  #pragma unroll
  for (int s = 0; s < 2; ++s)
    #pragma unroll
    for (int t = 0; t < 2; ++t)
      #pragma unroll
      for (int c = 0; c < 4; ++c){
        short8v f;
        #pragma unroll
        for (int r = 0; r < 8; ++r){
          int k = s*64 + t*32 + kg*8 + r;
          f[r] = (short)f2bf(W[k*DIM + c*16 + c16]);
        }
        Bf[s][t][c] = f;
      }
  float bc[4];
  #pragma unroll
  for (int c = 0; c < 4; ++c) bc[c] = bias[c*16 + c16];

  float ssum[4] = {0,0,0,0}, ssq[4] = {0,0,0,0};
  const int ntile = RN/16;
  for (int tile = gw; tile < ntile; tile += nw){
    int r0 = tile*16;
    int ar = r0 + c16;                               // A row for this lane
    short8v A00 = ((const short8v*)Xd)[ar*8 + kg];       // k 0..31
    short8v A01 = ((const short8v*)Xd)[ar*8 + 4 + kg];   // k 32..63
    short8v A10 = ((const short8v*)Ag)[ar*8 + kg];
    short8v A11 = ((const short8v*)Ag)[ar*8 + 4 + kg];
    f32x4 acc[4];
    #pragma unroll
    for (int c = 0; c < 4; ++c){ f32x4 z = {bc[c],bc[c],bc[c],bc[c]}; acc[c] = z; }
    #pragma unroll
    for (int c = 0; c < 4; ++c){
      acc[c] = __builtin_amdgcn_mfma_f32_16x16x32_bf16(A00, Bf[0][0][c], acc[c], 0, 0, 0);
      acc[c] = __builtin_amdgcn_mfma_f32_16x16x32_bf16(A01, Bf[0][1][c], acc[c], 0, 0, 0);
      acc[c] = __builtin_amdgcn_mfma_f32_16x16x32_bf16(A10, Bf[1][0][c], acc[c], 0, 0, 0);
      acc[c] = __builtin_amdgcn_mfma_f32_16x16x32_bf16(A11, Bf[1][1][c], acc[c], 0, 0, 0);
    }
    int orow = r0 + kg*4;   // C layout: col = lane&15, row = (lane>>4)*4 + reg  [m89-verified]
    #pragma unroll
    for (int c = 0; c < 4; ++c)
      #pragma unroll
      for (int r = 0; r < 4; ++r){
        float v = acc[c][r];
        ssum[c] += v; ssq[c] += v*v;
        __builtin_nontemporal_store(f2bf(v), &Hout[(size_t)(orow + r)*DIM + c*16 + c16]);
      }
  }
  #pragma unroll
  for (int c = 0; c < 4; ++c){
    atomicAdd(&ls[c*16 + c16], ssum[c]);
    atomicAdd(&ls[64 + c*16 + c16], ssq[c]);
  }
  __syncthreads();
  for (int t0 = threadIdx.x; t0 < 128; t0 += 256) atomicAdd(&stats[t0], ls[t0]);
}

// ---- BN finalize: a = g*rsqrt(var+eps), c = be - mu*a ----
__global__ __launch_bounds__(64) void bnfin_k(const float* stats, const float* g,
                                              const float* be, float* ac){
  int j = threadIdx.x;
  if (j >= 64) return;
  float mu  = stats[j]    * (1.0f/RN);
  float var = stats[64+j] * (1.0f/RN) - mu*mu;
  float inv = rsqrtf(var + 1e-5f);
  float a = g[j] * inv;
  ac[j] = a;
  ac[64+j] = be[j] - mu*a;
}

// ---- BN + SiLU, in-place on internal bf16 buffer (layer 1) ----
__global__ __launch_bounds__(256) void bnapply_k(unsigned short* H, const float* __restrict__ ac, int n8){
  int i = blockIdx.x*256 + threadIdx.x;
  if (i >= n8) return;
  us8 v = ((us8*)H)[i];
  int cb = (i*8) & 63;
  #pragma unroll
  for (int r = 0; r < 8; ++r){
    float x = bf2f(v[r]);
    float y = ac[cb+r]*x + ac[64+cb+r];
    float o = y / (1.0f + expf(-y));
    v[r] = f2bf(o);
  }
  __builtin_nontemporal_store(v, (us8*)H + i);
}

// ---- BN + SiLU to d_out (dtype per flag) ----
__global__ __launch_bounds__(256) void bnout_k(const unsigned short* __restrict__ H,
                                               const float* __restrict__ ac,
                                               void* out, long long ooff,
                                               const int* __restrict__ flags, int n8){
  int i = blockIdx.x*256 + threadIdx.x;
  if (i >= n8) return;
  us8 v = ((const us8*)H)[i];
  int cb = (i*8) & 63;
  float o[8];
  #pragma unroll
  for (int r = 0; r < 8; ++r){
    float x = bf2f(v[r]);
    float y = ac[cb+r]*x + ac[64+cb+r];
    o[r] = y / (1.0f + expf(-y));
  }
  if (flags[0]){
    unsigned short* ob = (unsigned short*)out + ooff + (long long)i*8;
    us8 w;
    #pragma unroll
    for (int r = 0; r < 8; ++r) w[r] = f2bf(o[r]);
    __builtin_nontemporal_store(w, (us8*)ob);
  } else {
    float* ob = (float*)out + ooff + (long long)i*8;
    f32x4 w0 = {o[0],o[1],o[2],o[3]}, w1 = {o[4],o[5],o[6],o[7]};
    __builtin_nontemporal_store(w0, (f32x4*)ob);
    __builtin_nontemporal_store(w1, (f32x4*)ob + 1);
  }
}

extern "C" void kernel_launch(void* const* d_in, const int* in_sizes, int n_in,
                              void* d_out, int out_size, void* d_ws, size_t ws_size,
                              hipStream_t stream){
  (void)in_sizes; (void)n_in; (void)out_size;
  const void* user_emb = d_in[0];
  const void* item_emb = d_in[1];
  const void* go_src   = d_in[18];
  const void* go_dst   = d_in[19];
  const void* back_src = d_in[20];
  const void* back_dst = d_in[21];

  char* ws = (char*)d_ws;
  size_t off = 0;
  auto alloc = [&](size_t bytes) -> void* {
    void* p = ws + off;
    off += (bytes + 255) & ~((size_t)255);
    return p;
  };
  int*   flags  = (int*)  alloc(64);
  float* params = (float*)alloc((size_t)49920*4);
  float* bnac   = (float*)alloc(512*4);
  int*   bcnt   = (int*)  alloc((size_t)6272*4);   // NSEG=6256 padded; stats follows contiguously
  float* stats  = (float*)alloc(512*4);
  int*   pseg   = (int*)  alloc((size_t)(NSEG+1)*4);
  int*   pcur   = (int*)  alloc((size_t)NSEG*4);
  int*   rs_all = (int*)  alloc((size_t)(NR2+1)*4);
  int*   col_all= (int*)  alloc((size_t)2*NE*4);
  unsigned short* user_bf = (unsigned short*)alloc((size_t)RN*DIM*2);
  unsigned short* item_bf = (unsigned short*)alloc((size_t)RN*DIM*2);
  unsigned short* x2u     = (unsigned short*)alloc((size_t)RN*DIM*2);
  unsigned short* x2i     = (unsigned short*)alloc((size_t)RN*DIM*2);
  unsigned short* agg     = (unsigned short*)alloc((size_t)RN*DIM*2);
  if (off > ws_size) return;  // ws too small: visible as absmax == 5.8125

  uint2* pairs = (uint2*)agg;   // 16MB alias; pairs dead before first spmm writes agg

  int* rs_go = rs_all;
  int* rs_bk = rs_all + RN;

  const int GE2 = (2*NE + 255)/256;        // 7813: both relations, one dispatch
  const int G8  = (RN*DIM/8)/256;          // 6250
  const int GS  = RN*64/256;               // 50000: one wave per row

  float* W_go1 = params + 0;     float* b_go1 = params + 12288;
  float* W_bk1 = params + 12352; float* b_bk1 = params + 24640;
  float* W_go2 = params + 24704; float* b_go2 = params + 36992;
  float* W_bk2 = params + 37056; float* b_bk2 = params + 49344;
  float* g1u = params + 49408; float* be1u = params + 49472;
  float* g1i = params + 49536; float* be1i = params + 49600;
  float* g2u = params + 49664; float* be2u = params + 49728;
  float* g2i = params + 49792; float* be2i = params + 49856;

  detect_k<<<1,256,0,stream>>>((const unsigned short*)user_emb, (const unsigned int*)go_src, flags);
  zero_k<<<(6272+512+255)/256,256,0,stream>>>(bcnt, 6272 + 512);   // bcnt + stats in one pass
  Ptrs16 ps;
  for (int i = 0; i < 16; ++i) ps.p[i] = d_in[2+i];
  conv_params_k<<<196,256,0,stream>>>(ps, flags, params);
  conv_emb_k<<<G8,256,0,stream>>>(user_emb, user_bf, flags, RN*DIM/8);
  conv_emb_k<<<G8,256,0,stream>>>(item_emb, item_bf, flags, RN*DIM/8);

  // ---- CSR build (XCD-local two-phase) ----
  countA_k<<<GE2,256,0,stream>>>((const unsigned int*)go_dst, (const unsigned int*)back_dst, bcnt, flags);
  scanTiny_k<<<1,1024,0,stream>>>(bcnt, pseg, pcur, rs_all);
  scatterA_k<<<GE2,256,0,stream>>>((const unsigned int*)go_src, (const unsigned int*)go_dst,
                                   (const unsigned int*)back_src, (const unsigned int*)back_dst,
                                   pcur, pairs, flags);
  buildCSR_k<<<NB,512,0,stream>>>(pseg, pairs, rs_all, col_all);

  // ---- layer 1 ----
  spmm_k<<<GS,256,0,stream>>>(rs_go, col_all, user_bf, agg);
  gemm_k<<<1024,256,0,stream>>>(item_bf, agg, W_go1, b_go1, x2i, stats + 0);
  bnfin_k<<<1,64,0,stream>>>(stats + 0, g1i, be1i, bnac + 0);
  bnapply_k<<<G8,256,0,stream>>>(x2i, bnac + 0, RN*DIM/8);

  spmm_k<<<GS,256,0,stream>>>(rs_bk, col_all, item_bf, agg);
  gemm_k<<<1024,256,0,stream>>>(user_bf, agg, W_bk1, b_bk1, x2u, stats + 128);
  bnfin_k<<<1,64,0,stream>>>(stats + 128, g1u, be1u, bnac + 128);
  bnapply_k<<<G8,256,0,stream>>>(x2u, bnac + 128, RN*DIM/8);

  // ---- layer 2 (GEMMs write in-place into agg; items first, then users) ----
  spmm_k<<<GS,256,0,stream>>>(rs_go, col_all, x2u, agg);
  gemm_k<<<1024,256,0,stream>>>(x2i, agg, W_go2, b_go2, agg, stats + 256);
  bnfin_k<<<1,64,0,stream>>>(stats + 256, g2i, be2i, bnac + 256);
  bnout_k<<<G8,256,0,stream>>>(agg, bnac + 256, d_out, (long long)RN*DIM, flags, RN*DIM/8);

  spmm_k<<<GS,256,0,stream>>>(rs_bk, col_all, x2i, agg);
  gemm_k<<<1024,256,0,stream>>>(x2u, agg, W_bk2, b_bk2, agg, stats + 384);
  bnfin_k<<<1,64,0,stream>>>(stats + 384, g2u, be2u, bnac + 384);
  bnout_k<<<G8,256,0,stream>>>(agg, bnac + 384, d_out, 0LL, flags, RN*DIM/8);
}

// Round 5
// 519.806 us; speedup vs baseline: 1.4216x; 1.4216x over previous
//
#include <hip/hip_runtime.h>
#include <cstdint>
#include <cstddef>

#define RN 200000   // nodes per side (NU == NI)
#define NR2 400000  // both sides
#define DIM 64
#define NE 1000000  // edges per relation
#define NB_PR 391   // buckets per relation (512 rows each; 391*512 >= 200000)
#define NBB 782     // total buckets (go: 0..390, back: 391..781)
#define ET 4096     // edges per sort block
#define NBLK 489    // ceil(2*NE / ET)
#define NBLKP 512   // padded row length of C/Rloc (bucket-major)

typedef __attribute__((ext_vector_type(8))) short short8v;   // 8 x bf16 fragment (4 VGPR)
typedef __attribute__((ext_vector_type(4))) float f32x4;
typedef __attribute__((ext_vector_type(8))) unsigned short us8;

struct Ptrs16 { const void* p[16]; };

__device__ __forceinline__ float bf2f(unsigned short u){
  unsigned int x = ((unsigned int)u) << 16;
  return __builtin_bit_cast(float, x);
}
__device__ __forceinline__ unsigned short f2bf(float f){
  unsigned int x = __builtin_bit_cast(unsigned int, f);
  unsigned int r = x + 0x7fffu + ((x >> 16) & 1u);   // RNE
  return (unsigned short)(r >> 16);
}

// ---- dtype sniffing: flags[0]=1 if floats are bf16, flags[1]=1 if indices are int64 ----
__global__ __launch_bounds__(256) void detect_k(const unsigned short* emb,
                                                const unsigned int* esrc,
                                                int* flags){
  __shared__ int cnt0, cnt1;
  int t = threadIdx.x;
  if (t == 0){ cnt0 = 0; cnt1 = 0; }
  __syncthreads();
  int c0 = 0, c1 = 0;
  #pragma unroll
  for (int s = 0; s < 4; ++s){
    int i = (t*4 + s) * 14;                 // even uint16 index
    float af = fabsf(bf2f(emb[i]));
    if (af > 0.0009765625f && af < 32.0f) c0++;
    int e = t*4 + s;
    if (esrc[2*e + 1] != 0u) c1++;          // int64 high words are 0
  }
  atomicAdd(&cnt0, c0); atomicAdd(&cnt1, c1);
  __syncthreads();
  if (t == 0){
    flags[0] = (cnt0 > 512) ? 1 : 0;
    flags[1] = (cnt1 < 512) ? 1 : 0;
  }
}

__global__ __launch_bounds__(256) void zero_k(int* p, int n){
  int i = blockIdx.x*256 + threadIdx.x;
  if (i < n) p[i] = 0;
}

// ---- canonicalize the 16 small param arrays (inputs 2..17) to fp32 ----
__global__ __launch_bounds__(256) void conv_params_k(Ptrs16 ps, const int* flags, float* out){
  const int offs[17] = {0,12288,12352,24640,24704,36992,37056,49344,49408,49472,
                        49536,49600,49664,49728,49792,49856,49920};
  int i = blockIdx.x*256 + threadIdx.x;
  if (i >= 49920) return;
  int a = 0;
  while (i >= offs[a+1]) ++a;
  int j = i - offs[a];
  float v = flags[0] ? bf2f(((const unsigned short*)ps.p[a])[j])
                     : ((const float*)ps.p[a])[j];
  out[i] = v;
}

// ---- canonicalize embeddings to internal bf16 ----
__global__ __launch_bounds__(256) void conv_emb_k(const void* in, unsigned short* out,
                                                  const int* flags, int n8){
  int i = blockIdx.x*256 + threadIdx.x;
  if (i >= n8) return;
  us8 o;
  if (flags[0]){
    o = ((const us8*)in)[i];
  } else {
    const float* f = (const float*)in + (size_t)i*8;
    #pragma unroll
    for (int r = 0; r < 8; ++r) o[r] = f2bf(f[r]);
  }
  ((us8*)out)[i] = o;
}

// ==== CSR build R5: block-local counting sort, ZERO per-edge global atomics ====
// Pass 1: per 4096-edge tile, LDS bucket histogram -> C[b][blk] (counts) and
// Rloc[b][blk] (tile-local exclusive prefix), bucket-major layout.
__global__ __launch_bounds__(256) void pass1_k(const unsigned int* go_dst,
                                               const unsigned int* back_dst,
                                               int* __restrict__ C, int* __restrict__ Rloc,
                                               const int* flags){
  __shared__ int h[1024];
  __shared__ int ps[256];
  int blk = blockIdx.x, t = threadIdx.x;
  #pragma unroll
  for (int q = 0; q < 4; ++q) h[t + q*256] = 0;
  __syncthreads();
  int i64 = flags[1];
  int e0 = blk*ET;
  #pragma unroll
  for (int j = 0; j < 16; ++j){
    int e = e0 + j*256 + t;
    if (e < 2*NE){
      int rel = e >= NE;
      int ei = rel ? e - NE : e;
      const unsigned int* pd = rel ? back_dst : go_dst;
      int d = i64 ? (int)pd[2*ei] : (int)pd[ei];
      int b = (rel ? NB_PR : 0) + (d >> 9);
      atomicAdd(&h[b], 1);
    }
  }
  __syncthreads();
  int c4[4], p4[4]; int s = 0;
  #pragma unroll
  for (int q = 0; q < 4; ++q){ c4[q] = h[t*4 + q]; p4[q] = s; s += c4[q]; }
  ps[t] = s;
  __syncthreads();
  for (int o = 1; o < 256; o <<= 1){
    int x = (t >= o) ? ps[t-o] : 0;
    __syncthreads();
    ps[t] += x;
    __syncthreads();
  }
  int base = (t > 0) ? ps[t-1] : 0;
  #pragma unroll
  for (int q = 0; q < 4; ++q){
    int b = t*4 + q;
    if (b < NBB){
      C[b*NBLKP + blk]    = c4[q];
      Rloc[b*NBLKP + blk] = base + p4[q];
    }
  }
}

// bucket sizes: one wave per bucket, coalesced row sum of C
__global__ __launch_bounds__(256) void sizes_k(const int* __restrict__ C, int* __restrict__ S){
  int w = blockIdx.x*4 + (threadIdx.x >> 6);
  int lane = threadIdx.x & 63;
  if (w >= NBB) return;
  int sum = 0;
  for (int k = lane; k < NBLK; k += 64) sum += C[w*NBLKP + k];
  #pragma unroll
  for (int o = 32; o > 0; o >>= 1) sum += __shfl_down(sum, o, 64);
  if (lane == 0) S[w] = sum;
}

// exclusive scan of the 782 bucket sizes -> s0 (bucket col base)
__global__ __launch_bounds__(1024) void scanS_k(const int* __restrict__ S, int* __restrict__ s0,
                                                int* __restrict__ rs){
  __shared__ int sh[1024];
  int t = threadIdx.x;
  int v = (t < NBB) ? S[t] : 0;
  sh[t] = v;
  __syncthreads();
  for (int o = 1; o < 1024; o <<= 1){
    int x = (t >= o) ? sh[t-o] : 0;
    __syncthreads();
    sh[t] += x;
    __syncthreads();
  }
  if (t < NBB) s0[t] = sh[t] - v;
  if (t == NBB-1){ s0[NBB] = sh[t]; rs[NR2] = 2*NE; }
}

// Pass 2: re-read tile, write packed (src | row_in_bucket<<18) into the
// block's PRIVATE 16KB slab region, grouped by bucket. LDS cursors only.
__global__ __launch_bounds__(256) void pass2_k(const unsigned int* go_src, const unsigned int* go_dst,
                                               const unsigned int* back_src, const unsigned int* back_dst,
                                               const int* __restrict__ Rloc,
                                               unsigned int* __restrict__ slab, const int* flags){
  __shared__ int lcur[1024];
  int blk = blockIdx.x, t = threadIdx.x;
  for (int b = t; b < NBB; b += 256) lcur[b] = Rloc[b*NBLKP + blk];
  __syncthreads();
  int i64 = flags[1];
  int e0 = blk*ET;
  #pragma unroll
  for (int j = 0; j < 16; ++j){
    int e = e0 + j*256 + t;
    if (e < 2*NE){
      int rel = e >= NE;
      int ei = rel ? e - NE : e;
      const unsigned int* pd = rel ? back_dst : go_dst;
      const unsigned int* psr = rel ? back_src : go_src;
      int d  = i64 ? (int)pd[2*ei]  : (int)pd[ei];
      int sc = i64 ? (int)psr[2*ei] : (int)psr[ei];
      int b = (rel ? NB_PR : 0) + (d >> 9);
      int r = d & 511;
      int pos = atomicAdd(&lcur[b], 1);
      slab[(size_t)blk*ET + pos] = (unsigned)sc | ((unsigned)r << 18);
    }
  }
}

// Per bucket: gather its 489 runs from the slabs (LDS binary search over run
// offsets), LDS row-histogram + scan -> rs, then scatter col sequentially.
__global__ __launch_bounds__(512) void buildCSR2_k(const int* __restrict__ C,
                                                   const int* __restrict__ Rloc,
                                                   const int* __restrict__ s0g,
                                                   const unsigned int* __restrict__ slab,
                                                   int* __restrict__ rs, int* __restrict__ col){
  __shared__ int cblk[NBLKP], rblk[NBLKP], off[NBLKP];
  __shared__ int lcnt[512], lsc[512], lcur[512];
  int b = blockIdx.x, t = threadIdx.x;
  cblk[t] = (t < NBLK) ? C[b*NBLKP + t] : 0;
  rblk[t] = (t < NBLK) ? Rloc[b*NBLKP + t] : 0;
  lcnt[t] = 0;
  int v = cblk[t];
  off[t] = v;
  __syncthreads();
  for (int o = 1; o < 512; o <<= 1){
    int x = (t >= o) ? off[t-o] : 0;
    __syncthreads();
    off[t] += x;
    __syncthreads();
  }
  int Sb = off[511];
  int excl = off[t] - v;
  __syncthreads();
  off[t] = excl;                       // exclusive run starts within bucket
  __syncthreads();
  int s0b = s0g[b];
  int d0 = (b < NB_PR) ? b*512 : RN + (b - NB_PR)*512;
  int relEnd = (b < NB_PR) ? RN : NR2;
  int rows = relEnd - d0; if (rows > 512) rows = 512;
  // pass 1: row histogram
  for (int i = t; i < Sb; i += 512){
    int lo = 0;
    #pragma unroll
    for (int st = 256; st > 0; st >>= 1){
      int nx = lo + st;
      if (nx < 512 && off[nx] <= i) lo = nx;
    }
    unsigned int q = slab[(size_t)lo*ET + rblk[lo] + (i - off[lo])];
    atomicAdd(&lcnt[q >> 18], 1);
  }
  __syncthreads();
  int rv = lcnt[t];
  lsc[t] = rv;
  __syncthreads();
  for (int o = 1; o < 512; o <<= 1){
    int x = (t >= o) ? lsc[t-o] : 0;
    __syncthreads();
    lsc[t] += x;
    __syncthreads();
  }
  int start = lsc[t] - rv;
  lcur[t] = start;
  if (t < rows) rs[d0 + t] = s0b + start;
  __syncthreads();
  // pass 2: scatter col (sequential within bucket; L2/L3-hot slab re-read)
  for (int i = t; i < Sb; i += 512){
    int lo = 0;
    #pragma unroll
    for (int st = 256; st > 0; st >>= 1){
      int nx = lo + st;
      if (nx < 512 && off[nx] <= i) lo = nx;
    }
    unsigned int q = slab[(size_t)lo*ET + rblk[lo] + (i - off[lo])];
    int r = (int)(q >> 18);
    int p = atomicAdd(&lcur[r], 1);
    col[s0b + p] = (int)(q & 0x3FFFFu);
  }
}

// ---- SpMM: one wave per dst row; agg = deg^-1/2 * sum_src X[src] (bf16 out) ----
__global__ __launch_bounds__(256) void spmm_k(const int* __restrict__ rs, const int* __restrict__ col,
                                              const unsigned short* __restrict__ X,
                                              unsigned short* __restrict__ agg){
  int w = (int)((blockIdx.x*256 + threadIdx.x) >> 6);
  int lane = threadIdx.x & 63;
  if (w >= RN) return;
  int b = __builtin_amdgcn_readfirstlane(rs[w]);
  int e = __builtin_amdgcn_readfirstlane(rs[w+1]);
  float acc = 0.0f;
  for (int i = b; i < e; i += 8){
    int rem = e - i;                       // wave-uniform
    int idx0 = __builtin_nontemporal_load(&col[i]);
    int idx[8];
    idx[0] = idx0;
    #pragma unroll
    for (int j = 1; j < 8; ++j)
      idx[j] = (j < rem) ? __builtin_nontemporal_load(&col[i + j]) : idx0;  // clamp tail
    float v[8];
    #pragma unroll
    for (int j = 0; j < 8; ++j)
      v[j] = bf2f(X[((size_t)(unsigned)idx[j] << 6) + lane]);
    #pragma unroll
    for (int j = 0; j < 8; ++j)
      acc += (j < rem) ? v[j] : 0.0f;
  }
  int dg = e - b;
  float nrm = dg > 0 ? rsqrtf((float)dg) : 1.0f;
  __builtin_nontemporal_store(f2bf(acc * nrm), &agg[((size_t)w << 6) + lane]);
}

// ---- GEMM: H = Xd@W[0:64] + Ag@W[64:128] + b, bf16 out (maybe in-place into Ag),
//      fused BN sum/sumsq stats. Wave tile = 16 rows x 64 cols, mfma 16x16x32 bf16. ----
__global__ __launch_bounds__(256) void gemm_k(const unsigned short* __restrict__ Xd,
                                              const unsigned short* Ag,           // may alias Hout
                                              const float* __restrict__ W,
                                              const float* __restrict__ bias,
                                              unsigned short* Hout,
                                              float* __restrict__ stats){
  __shared__ float ls[128];
  for (int t0 = threadIdx.x; t0 < 128; t0 += 256) ls[t0] = 0.0f;
  __syncthreads();
  int lane = threadIdx.x & 63;
  int gw = (int)((blockIdx.x*256 + threadIdx.x) >> 6);
  int nw = (int)(gridDim.x * 4);
  int c16 = lane & 15, kg = lane >> 4;

  short8v Bf[2][2][4];
  #pragma unroll
  for (int s = 0; s < 2; ++s)
    #pragma unroll
    for (int t = 0; t < 2; ++t)
      #pragma unroll
      for (int c = 0; c < 4; ++c){
        short8v f;
        #pragma unroll
        for (int r = 0; r < 8; ++r){
          int k = s*64 + t*32 + kg*8 + r;
          f[r] = (short)f2bf(W[k*DIM + c*16 + c16]);
        }
        Bf[s][t][c] = f;
      }
  float bc[4];
  #pragma unroll
  for (int c = 0; c < 4; ++c) bc[c] = bias[c*16 + c16];

  float ssum[4] = {0,0,0,0}, ssq[4] = {0,0,0,0};
  const int ntile = RN/16;
  for (int tile = gw; tile < ntile; tile += nw){
    int r0 = tile*16;
    int ar = r0 + c16;
    short8v A00 = ((const short8v*)Xd)[ar*8 + kg];
    short8v A01 = ((const short8v*)Xd)[ar*8 + 4 + kg];
    short8v A10 = ((const short8v*)Ag)[ar*8 + kg];
    short8v A11 = ((const short8v*)Ag)[ar*8 + 4 + kg];
    f32x4 acc[4];
    #pragma unroll
    for (int c = 0; c < 4; ++c){ f32x4 z = {bc[c],bc[c],bc[c],bc[c]}; acc[c] = z; }
    #pragma unroll
    for (int c = 0; c < 4; ++c){
      acc[c] = __builtin_amdgcn_mfma_f32_16x16x32_bf16(A00, Bf[0][0][c], acc[c], 0, 0, 0);
      acc[c] = __builtin_amdgcn_mfma_f32_16x16x32_bf16(A01, Bf[0][1][c], acc[c], 0, 0, 0);
      acc[c] = __builtin_amdgcn_mfma_f32_16x16x32_bf16(A10, Bf[1][0][c], acc[c], 0, 0, 0);
      acc[c] = __builtin_amdgcn_mfma_f32_16x16x32_bf16(A11, Bf[1][1][c], acc[c], 0, 0, 0);
    }
    int orow = r0 + kg*4;   // C layout: col = lane&15, row = (lane>>4)*4 + reg  [m89-verified]
    #pragma unroll
    for (int c = 0; c < 4; ++c)
      #pragma unroll
      for (int r = 0; r < 4; ++r){
        float v = acc[c][r];
        ssum[c] += v; ssq[c] += v*v;
        __builtin_nontemporal_store(f2bf(v), &Hout[(size_t)(orow + r)*DIM + c*16 + c16]);
      }
  }
  #pragma unroll
  for (int c = 0; c < 4; ++c){
    atomicAdd(&ls[c*16 + c16], ssum[c]);
    atomicAdd(&ls[64 + c*16 + c16], ssq[c]);
  }
  __syncthreads();
  for (int t0 = threadIdx.x; t0 < 128; t0 += 256) atomicAdd(&stats[t0], ls[t0]);
}

// ---- BN finalize: a = g*rsqrt(var+eps), c = be - mu*a ----
__global__ __launch_bounds__(64) void bnfin_k(const float* stats, const float* g,
                                              const float* be, float* ac){
  int j = threadIdx.x;
  if (j >= 64) return;
  float mu  = stats[j]    * (1.0f/RN);
  float var = stats[64+j] * (1.0f/RN) - mu*mu;
  float inv = rsqrtf(var + 1e-5f);
  float a = g[j] * inv;
  ac[j] = a;
  ac[64+j] = be[j] - mu*a;
}

// ---- BN + SiLU, in-place on internal bf16 buffer (layer 1) ----
__global__ __launch_bounds__(256) void bnapply_k(unsigned short* H, const float* __restrict__ ac, int n8){
  int i = blockIdx.x*256 + threadIdx.x;
  if (i >= n8) return;
  us8 v = ((us8*)H)[i];
  int cb = (i*8) & 63;
  #pragma unroll
  for (int r = 0; r < 8; ++r){
    float x = bf2f(v[r]);
    float y = ac[cb+r]*x + ac[64+cb+r];
    float o = y / (1.0f + expf(-y));
    v[r] = f2bf(o);
  }
  __builtin_nontemporal_store(v, (us8*)H + i);
}

// ---- BN + SiLU to d_out (dtype per flag) ----
__global__ __launch_bounds__(256) void bnout_k(const unsigned short* __restrict__ H,
                                               const float* __restrict__ ac,
                                               void* out, long long ooff,
                                               const int* __restrict__ flags, int n8){
  int i = blockIdx.x*256 + threadIdx.x;
  if (i >= n8) return;
  us8 v = ((const us8*)H)[i];
  int cb = (i*8) & 63;
  float o[8];
  #pragma unroll
  for (int r = 0; r < 8; ++r){
    float x = bf2f(v[r]);
    float y = ac[cb+r]*x + ac[64+cb+r];
    o[r] = y / (1.0f + expf(-y));
  }
  if (flags[0]){
    unsigned short* ob = (unsigned short*)out + ooff + (long long)i*8;
    us8 w;
    #pragma unroll
    for (int r = 0; r < 8; ++r) w[r] = f2bf(o[r]);
    __builtin_nontemporal_store(w, (us8*)ob);
  } else {
    float* ob = (float*)out + ooff + (long long)i*8;
    f32x4 w0 = {o[0],o[1],o[2],o[3]}, w1 = {o[4],o[5],o[6],o[7]};
    __builtin_nontemporal_store(w0, (f32x4*)ob);
    __builtin_nontemporal_store(w1, (f32x4*)ob + 1);
  }
}

extern "C" void kernel_launch(void* const* d_in, const int* in_sizes, int n_in,
                              void* d_out, int out_size, void* d_ws, size_t ws_size,
                              hipStream_t stream){
  (void)in_sizes; (void)n_in; (void)out_size;
  const void* user_emb = d_in[0];
  const void* item_emb = d_in[1];
  const void* go_src   = d_in[18];
  const void* go_dst   = d_in[19];
  const void* back_src = d_in[20];
  const void* back_dst = d_in[21];

  char* ws = (char*)d_ws;
  size_t off = 0;
  auto alloc = [&](size_t bytes) -> void* {
    void* p = ws + off;
    off += (bytes + 255) & ~((size_t)255);
    return p;
  };
  int*   flags  = (int*)  alloc(64);
  float* params = (float*)alloc((size_t)49920*4);
  float* bnac   = (float*)alloc(512*4);
  float* stats  = (float*)alloc(512*4);
  int*   Cmat   = (int*)  alloc((size_t)NBB*NBLKP*4);   // 1.6MB
  int*   Rloc   = (int*)  alloc((size_t)NBB*NBLKP*4);   // 1.6MB
  int*   Sbuf   = (int*)  alloc(1024*4);
  int*   s0g    = (int*)  alloc(1024*4);
  int*   rs_all = (int*)  alloc((size_t)(NR2+1)*4);
  int*   col_all= (int*)  alloc((size_t)2*NE*4);
  unsigned short* user_bf = (unsigned short*)alloc((size_t)RN*DIM*2);
  unsigned short* item_bf = (unsigned short*)alloc((size_t)RN*DIM*2);
  unsigned short* x2u     = (unsigned short*)alloc((size_t)RN*DIM*2);
  unsigned short* x2i     = (unsigned short*)alloc((size_t)RN*DIM*2);
  unsigned short* agg     = (unsigned short*)alloc((size_t)RN*DIM*2);
  if (off > ws_size) return;  // ws too small: visible as absmax == 5.8125

  unsigned int* slab = (unsigned int*)agg;  // 8MB alias; slab dead before first spmm writes agg

  int* rs_go = rs_all;
  int* rs_bk = rs_all + RN;

  const int G8 = (RN*DIM/8)/256;          // 6250
  const int GS = RN*64/256;               // 50000: one wave per row

  float* W_go1 = params + 0;     float* b_go1 = params + 12288;
  float* W_bk1 = params + 12352; float* b_bk1 = params + 24640;
  float* W_go2 = params + 24704; float* b_go2 = params + 36992;
  float* W_bk2 = params + 37056; float* b_bk2 = params + 49344;
  float* g1u = params + 49408; float* be1u = params + 49472;
  float* g1i = params + 49536; float* be1i = params + 49600;
  float* g2u = params + 49664; float* be2u = params + 49728;
  float* g2i = params + 49792; float* be2i = params + 49856;

  detect_k<<<1,256,0,stream>>>((const unsigned short*)user_emb, (const unsigned int*)go_src, flags);
  zero_k<<<2,256,0,stream>>>((int*)stats, 512);
  Ptrs16 ps;
  for (int i = 0; i < 16; ++i) ps.p[i] = d_in[2+i];
  conv_params_k<<<196,256,0,stream>>>(ps, flags, params);
  conv_emb_k<<<G8,256,0,stream>>>(user_emb, user_bf, flags, RN*DIM/8);
  conv_emb_k<<<G8,256,0,stream>>>(item_emb, item_bf, flags, RN*DIM/8);

  // ---- CSR build (block-local counting sort, no global atomics) ----
  pass1_k<<<NBLK,256,0,stream>>>((const unsigned int*)go_dst, (const unsigned int*)back_dst,
                                 Cmat, Rloc, flags);
  sizes_k<<<(NBB+3)/4,256,0,stream>>>(Cmat, Sbuf);
  scanS_k<<<1,1024,0,stream>>>(Sbuf, s0g, rs_all);
  pass2_k<<<NBLK,256,0,stream>>>((const unsigned int*)go_src, (const unsigned int*)go_dst,
                                 (const unsigned int*)back_src, (const unsigned int*)back_dst,
                                 Rloc, slab, flags);
  buildCSR2_k<<<NBB,512,0,stream>>>(Cmat, Rloc, s0g, slab, rs_all, col_all);

  // ---- layer 1 ----
  spmm_k<<<GS,256,0,stream>>>(rs_go, col_all, user_bf, agg);
  gemm_k<<<1024,256,0,stream>>>(item_bf, agg, W_go1, b_go1, x2i, stats + 0);
  bnfin_k<<<1,64,0,stream>>>(stats + 0, g1i, be1i, bnac + 0);
  bnapply_k<<<G8,256,0,stream>>>(x2i, bnac + 0, RN*DIM/8);

  spmm_k<<<GS,256,0,stream>>>(rs_bk, col_all, item_bf, agg);
  gemm_k<<<1024,256,0,stream>>>(user_bf, agg, W_bk1, b_bk1, x2u, stats + 128);
  bnfin_k<<<1,64,0,stream>>>(stats + 128, g1u, be1u, bnac + 128);
  bnapply_k<<<G8,256,0,stream>>>(x2u, bnac + 128, RN*DIM/8);

  // ---- layer 2 (GEMMs write in-place into agg; items first, then users) ----
  spmm_k<<<GS,256,0,stream>>>(rs_go, col_all, x2u, agg);
  gemm_k<<<1024,256,0,stream>>>(x2i, agg, W_go2, b_go2, agg, stats + 256);
  bnfin_k<<<1,64,0,stream>>>(stats + 256, g2i, be2i, bnac + 256);
  bnout_k<<<G8,256,0,stream>>>(agg, bnac + 256, d_out, (long long)RN*DIM, flags, RN*DIM/8);

  spmm_k<<<GS,256,0,stream>>>(rs_bk, col_all, x2i, agg);
  gemm_k<<<1024,256,0,stream>>>(x2u, agg, W_bk2, b_bk2, agg, stats + 384);
  bnfin_k<<<1,64,0,stream>>>(stats + 384, g2u, be2u, bnac + 384);
  bnout_k<<<G8,256,0,stream>>>(agg, bnac + 384, d_out, 0LL, flags, RN*DIM/8);
}